// Round 8
// baseline (216.194 us; speedup 1.0000x reference)
//
#include <hip/hip_runtime.h>
#include <math.h>

#define N1 2000
#define N2 2000
#define NT 4000
#define D  63
#define E  64
#define H  8
#define KNN 5
#define NPAD 4032   // n padded: 63 blocks of 64
#define MPAD 4096   // m padded: 16 blocks of 256
#define NWIN 32     // knn col-windows: 32 windows of 64 cols

typedef short bf16x8 __attribute__((ext_vector_type(8)));
typedef float f32x4  __attribute__((ext_vector_type(4)));

__device__ __forceinline__ unsigned short f2bf(float x) {
    unsigned u = __float_as_uint(x);
    u = (u + 0x7fffu + ((u >> 16) & 1u)) >> 16;   // RN-even
    return (unsigned short)u;
}

// ---------------------------------------------------------------- knn helpers
__device__ __forceinline__ bool dless(float d1, int i1, float d2v, int i2) {
    return d1 < d2v || (d1 == d2v && i1 < i2);   // stable top_k tie-break
}

__device__ __forceinline__ void ins5(float bd[KNN], int bi[KNN], float d, int j) {
    if (dless(d, j, bd[KNN - 1], bi[KNN - 1])) {
        bd[KNN - 1] = d; bi[KNN - 1] = j;
        #pragma unroll
        for (int s = KNN - 1; s > 0; --s) {
            if (dless(bd[s], bi[s], bd[s - 1], bi[s - 1])) {
                float td = bd[s]; bd[s] = bd[s - 1]; bd[s - 1] = td;
                int ti = bi[s]; bi[s] = bi[s - 1]; bi[s - 1] = ti;
            }
        }
    }
}

// ---------------------------------------------------------------- k_knn
// Grid 32x32 = 1024 blocks: one 64x64 tile per block, single staging phase,
// 2 barriers, 4x4 register MAC (proven R2). Never materializes d2: per-row
// top-5 within this 64-col window via lane-local ins5 + 16-lane butterfly,
// written to part arrays (5 candidates per row per window).
__global__ __launch_bounds__(256) void k_knn(const float* __restrict__ X,
                                             float* __restrict__ part_d,
                                             int* __restrict__ part_i) {
    __shared__ float Xi[64][68];
    __shared__ float Xj[64][68];
    __shared__ float sqi[64];
    __shared__ float sqj[64];
    int cb = blockIdx.x, rb = blockIdx.y;
    int i0 = rb * 64, j0 = cb * 64;
    int tid = threadIdx.x;

    for (int t = tid; t < 64 * 64; t += 256) {
        int r = t >> 6, c = t & 63;
        int gi = min(i0 + r, N1 - 1);
        int gj = min(j0 + r, N1 - 1);
        Xi[r][c] = (c < D) ? X[gi * D + c] : 0.f;
        Xj[r][c] = (c < D) ? X[gj * D + c] : 0.f;
    }
    __syncthreads();
    if (tid < 128) {                              // sqi by lanes 0-63, sqj 64-127
        int r = tid & 63;
        const float* src = (tid < 64) ? &Xi[r][0] : &Xj[r][0];
        float s = 0.f;
        #pragma unroll
        for (int q = 0; q < 16; ++q) {
            float4 v = *(const float4*)&src[4 * q];
            s += v.x * v.x + v.y * v.y + v.z * v.z + v.w * v.w;
        }
        if (tid < 64) sqi[r] = s; else sqj[r] = s;
    }
    __syncthreads();

    int tx = tid & 15, ty = tid >> 4;
    float acc[4][4];
    #pragma unroll
    for (int a = 0; a < 4; ++a)
        #pragma unroll
        for (int b = 0; b < 4; ++b) acc[a][b] = 0.f;

    #pragma unroll 4
    for (int kk = 0; kk < 16; ++kk) {
        float4 av[4], bv[4];
        #pragma unroll
        for (int ii = 0; ii < 4; ++ii) av[ii] = *(const float4*)&Xi[ty + 16 * ii][4 * kk];
        #pragma unroll
        for (int jj = 0; jj < 4; ++jj) bv[jj] = *(const float4*)&Xj[tx + 16 * jj][4 * kk];
        #pragma unroll
        for (int ii = 0; ii < 4; ++ii)
            #pragma unroll
            for (int jj = 0; jj < 4; ++jj)
                acc[ii][jj] += av[ii].x * bv[jj].x + av[ii].y * bv[jj].y +
                               av[ii].z * bv[jj].z + av[ii].w * bv[jj].w;
    }

    // per-thread top-5 over this thread's 4 cols of each of its 4 rows
    float bd[4][KNN]; int bi[4][KNN];
    #pragma unroll
    for (int ii = 0; ii < 4; ++ii) {
        #pragma unroll
        for (int s = 0; s < KNN; ++s) { bd[ii][s] = __builtin_inff(); bi[ii][s] = 0x7fffffff; }
        int gi = i0 + ty + 16 * ii;
        float si = sqi[ty + 16 * ii];
        #pragma unroll
        for (int jj = 0; jj < 4; ++jj) {
            int gj = j0 + tx + 16 * jj;
            if (gj < N1 && gj != gi) {
                float dv = si + sqj[tx + 16 * jj] - 2.f * acc[ii][jj];
                ins5(bd[ii], bi[ii], dv, gj);
            }
        }
    }

    // merge the 16 per-lane lists of each row (16-lane butterfly, 5 extracts)
    #pragma unroll
    for (int ii = 0; ii < 4; ++ii) {
        float wd[KNN]; int wi[KNN];
        #pragma unroll
        for (int s = 0; s < KNN; ++s) {
            float d = bd[ii][0]; int ix = bi[ii][0];
            #pragma unroll
            for (int m = 1; m < 16; m <<= 1) {
                float od = __shfl_xor(d, m, 64);
                int   oi = __shfl_xor(ix, m, 64);
                if (dless(od, oi, d, ix)) { d = od; ix = oi; }
            }
            wd[s] = d; wi[s] = ix;
            if (d == bd[ii][0] && ix == bi[ii][0]) {
                #pragma unroll
                for (int q = 0; q < KNN - 1; ++q) { bd[ii][q] = bd[ii][q + 1]; bi[ii][q] = bi[ii][q + 1]; }
                bd[ii][KNN - 1] = __builtin_inff(); bi[ii][KNN - 1] = 0x7fffffff;
            }
        }
        if (tx == 0) {
            int row = i0 + ty + 16 * ii;
            if (row < N1) {
                #pragma unroll
                for (int s = 0; s < KNN; ++s) {
                    part_d[row * (NWIN * KNN) + cb * KNN + s] = wd[s];
                    part_i[row * (NWIN * KNN) + cb * KNN + s] = wi[s];
                }
            }
        }
    }
}

// ---------------------------------------------------------------- k_mgprep
// FUSED k_merge + k_prep (stream order guarantees part arrays are complete).
// Blocks < 500: first merge 4 rows (one wave per row, 32x5=160 candidates,
// 3-deep lane lists) -> ypred + idx. All 1000 blocks: prep for 4 nodes
// (1 per wave); W_emb staged in LDS. AL fold: +1/||a||. Bbuf = bf16(e).
__global__ __launch_bounds__(256) void k_mgprep(const float* __restrict__ part_d,
                                                const int* __restrict__ part_i,
                                                const float* __restrict__ lmY,
                                                float* __restrict__ ypred,
                                                int* __restrict__ idx,
                                                const float* __restrict__ lmX,
                                                const float* __restrict__ tgX,
                                                const float* __restrict__ lmD,
                                                const float* __restrict__ tgD,
                                                const float* __restrict__ W,
                                                const float* __restrict__ bias,
                                                const float* __restrict__ w1,
                                                const float* __restrict__ w2,
                                                unsigned short* __restrict__ AL,
                                                unsigned short* __restrict__ Bbuf,
                                                float* __restrict__ sB) {
    int tid = threadIdx.x, lane = tid & 63, wave = tid >> 6;

    // ---- merge phase (blocks 0..499) ----
    if (blockIdx.x < 500) {
        int row = blockIdx.x * 4 + wave;           // rows < 2000
        float ld[3]; int li[3];
        #pragma unroll
        for (int q = 0; q < 3; ++q) {
            int c = lane + 64 * q;
            if (c < NWIN * KNN) {
                ld[q] = part_d[row * (NWIN * KNN) + c];
                li[q] = part_i[row * (NWIN * KNN) + c];
            } else { ld[q] = __builtin_inff(); li[q] = 0x7fffffff; }
        }
        #pragma unroll
        for (int a = 0; a < 2; ++a)
            #pragma unroll
            for (int q = 0; q < 2; ++q)
                if (dless(ld[q + 1], li[q + 1], ld[q], li[q])) {
                    float td = ld[q]; ld[q] = ld[q + 1]; ld[q + 1] = td;
                    int ti = li[q]; li[q] = li[q + 1]; li[q + 1] = ti;
                }
        float d = ld[0]; int ix = li[0]; int p = 0;
        float rd[KNN]; int ri[KNN];
        #pragma unroll
        for (int s = 0; s < KNN; ++s) {
            float md = d; int mi = ix;
            #pragma unroll
            for (int m = 1; m < 64; m <<= 1) {
                float od = __shfl_xor(md, m, 64);
                int   oi = __shfl_xor(mi, m, 64);
                if (dless(od, oi, md, mi)) { md = od; mi = oi; }
            }
            rd[s] = md; ri[s] = mi;
            if (md == d && mi == ix) {             // this lane won: advance
                ++p;
                d  = (p < 3) ? ld[p] : __builtin_inff();
                ix = (p < 3) ? li[p] : 0x7fffffff;
            }
        }
        if (lane == 0) {
            float y0 = 0.f, y1 = 0.f;
            #pragma unroll
            for (int s = 0; s < KNN; ++s) {
                int j = ri[s];
                y0 += lmY[j * 2];
                y1 += lmY[j * 2 + 1];
                idx[row * KNN + s] = j;
            }
            ypred[row * 2]     = y0 * 0.2f;
            ypred[row * 2 + 1] = y1 * 0.2f;
        }
    }

    // ---- prep phase (all 1000 blocks, 4 nodes each) ----
    __shared__ float f[4][E];
    __shared__ float Wl[E][68];
    int n = blockIdx.x * 4 + wave;       // n < 4000
    #pragma unroll
    for (int k = 0; k < 4; ++k) {        // 1024 float4s, 4/thread, coalesced
        int g = k * 256 + tid;
        float4 v = ((const float4*)W)[g];
        int r = g >> 4, c = (g & 15) * 4;
        *(float4*)&Wl[r][c] = v;
    }
    int t = lane;
    if (t < D)  f[wave][t] = (n < N1) ? lmX[n * D + t] : tgX[(n - N1) * D + t];
    if (t == D) f[wave][t] = (n < N1) ? lmD[n] : tgD[n - N1];
    __syncthreads();
    float s0 = 0.f, s1 = 0.f, s2 = 0.f, s3 = 0.f;
    #pragma unroll
    for (int k = 0; k < 16; ++k) {
        float4 wv = *(const float4*)&Wl[t][4 * k];
        float4 fv = *(const float4*)&f[wave][4 * k];
        s0 += fv.x * wv.x; s1 += fv.y * wv.y; s2 += fv.z * wv.z; s3 += fv.w * wv.w;
    }
    const float en = bias[t] + (s0 + s1) + (s2 + s3);
    Bbuf[n * E + t] = f2bf(en);

    int kc = t >> 5, kq = (t >> 3) & 3, j = t & 7;
    int alane = kq * 16 + (n & 15);
    int nb = n >> 4;
    #pragma unroll
    for (int h = 0; h < H; ++h) {
        float a = en * w1[t * H + h];
        float b = en * w2[t * H + h];
        float na2 = a * a, nb2 = b * b;
        #pragma unroll
        for (int m = 32; m >= 1; m >>= 1) {
            na2 += __shfl_xor(na2, m, 64);
            nb2 += __shfl_xor(nb2, m, 64);
        }
        float val = a * w2[t * H + h] * rsqrtf(na2);   // folds 1/||a||
        AL[(((nb * 8 + h) << 1) + kc) * 512 + alane * 8 + j] = f2bf(val);
        if (t == h) sB[n * H + h] = rsqrtf(nb2);
    }
}

// ---------------------------------------------------------------- k_adjm
// Block: 4 waves, tile 64(n) x 256(m). B tile in LDS, A frags in registers.
// Head-halved epilogue (proven R3), __launch_bounds__(256,4).
// Polynomial sigmoid (sim in [-1,1], |err|<=5e-5).
// NEW (isolated change vs R7): the adj_teacher base-pattern fill is
// interleaved into the mt loop -- per mt, each wave fills one full 1024B
// row (4 rows/block/mt, 64 rows over 16 mt). Rationale: k_adjm is
// latency-bound (all pipes <35%, stores ~2.4 TB/s during the loop) and with
// ~1 dispatch round the tail fill was a chip-wide serialized store burst.
// Stores are fire-and-forget; no extra registers/sync. Scatter ordering is
// still guaranteed by the pre-scatter __syncthreads (drains vmcnt).
__global__ __launch_bounds__(256, 4) void k_adjm(const unsigned short* __restrict__ AL,
                                                 const unsigned short* __restrict__ Bbuf,
                                                 const float* __restrict__ sB,
                                                 const int* __restrict__ idx,
                                                 float* __restrict__ adj,
                                                 float* __restrict__ adjT) {
    __shared__ unsigned short Bt[256][68];   // 34,816 B -> 4 blocks/CU
    int tid = threadIdx.x;
    int m0 = blockIdx.x * 256, n0 = blockIdx.y * 64;

    #pragma unroll
    for (int it = 0; it < 8; ++it) {
        int g = it * 256 + tid;
        int row = g >> 3, c = g & 7;
        *(bf16x8*)&Bt[row][c * 8] = *(const bf16x8*)&Bbuf[(m0 + row) * E + c * 8];
    }

    int wave = tid >> 6, lane = tid & 63;
    int l15 = lane & 15, kq = lane >> 4;
    int nb = blockIdx.y * 4 + wave;

    bf16x8 afr[H][2];
    #pragma unroll
    for (int h = 0; h < H; ++h)
        #pragma unroll
        for (int kc = 0; kc < 2; ++kc)
            afr[h][kc] = *(const bf16x8*)&AL[(((nb * 8 + h) << 1) + kc) * 512 + lane * 8];

    __syncthreads();

    int nebase = n0 + wave * 16 + kq * 4;
    // adjT interleaved-fill mapping: per mt, wave w fills row n0+mt*4+w... no:
    // row = n0 + mt*4 + wave covers rows n0..n0+63 over mt=0..15, one full
    // 256-col row per wave per mt (64 lanes x float4 = 1024B contiguous).
    int tcol = m0 + lane * 4;

    #pragma unroll 1
    for (int mt = 0; mt < 16; ++mt) {
        // ---- adjT base-pattern stripe (overlaps the compute/store loop) ----
        {
            int row = n0 + mt * 4 + wave;
            if (row < NT && tcol < NT) {
                float v = ((row < N1) != (tcol < N1)) ? 1.f : 0.f;
                float4 o = {v, v, v, v};
                *(float4*)&adjT[row * NT + tcol] = o;
            }
        }

        int mrow = mt * 16 + l15;
        int mcol = m0 + mrow;
        bf16x8 b0 = *(const bf16x8*)&Bt[mrow][kq * 8];
        bf16x8 b1 = *(const bf16x8*)&Bt[mrow][32 + kq * 8];

        float sum[4] = {0.f, 0.f, 0.f, 0.f};
        #pragma unroll
        for (int hh = 0; hh < 2; ++hh) {
            float sbv[4];
            *(f32x4*)&sbv[0] = *(const f32x4*)&sB[mcol * H + hh * 4];
            f32x4 acc[4];
            #pragma unroll
            for (int h4 = 0; h4 < 4; ++h4) {
                int h = hh * 4 + h4;
                acc[h4] = (f32x4){0.f, 0.f, 0.f, 0.f};
                acc[h4] = __builtin_amdgcn_mfma_f32_16x16x32_bf16(afr[h][0], b0, acc[h4], 0, 0, 0);
                acc[h4] = __builtin_amdgcn_mfma_f32_16x16x32_bf16(afr[h][1], b1, acc[h4], 0, 0, 0);
            }
            #pragma unroll
            for (int reg = 0; reg < 4; ++reg) {
                #pragma unroll
                for (int h4 = 0; h4 < 4; ++h4) {
                    float x = acc[h4][reg] * sbv[h4];             // sim, in [-1,1]
                    float u = x * x;
                    float p = fmaf(u, 1.8919e-3f, -2.0833333e-2f);
                    p = fmaf(u, p, 0.25f);
                    sum[reg] = fmaf(x, p, sum[reg]);              // += sigma(x)-0.5
                }
            }
        }

        bool mok = (mcol < NT);
        #pragma unroll
        for (int reg = 0; reg < 4; ++reg) {
            int ne = nebase + reg;
            if (mok && ne < NT) adj[ne * NT + mcol] = fmaf(sum[reg], 0.125f, 0.5f);
        }
    }

    __syncthreads();                             // order scatter after fill
    // ---- KNN scatter: rows n0..n0+63 (lm only), cols within this tile ----
    for (int p = tid; p < 64 * KNN; p += 256) {
        int r = p / KNN, s = p - r * KNN;
        int row = n0 + r;
        if (row < N1) {
            int jx = idx[row * KNN + s];
            if (jx >= m0 && jx < m0 + 256) adjT[row * NT + jx] = 1.f;
        }
    }
}

// ---------------------------------------------------------------- launch
extern "C" void kernel_launch(void* const* d_in, const int* in_sizes, int n_in,
                              void* d_out, int out_size, void* d_ws, size_t ws_size,
                              hipStream_t stream) {
    const float* lmX  = (const float*)d_in[0];
    const float* lmY  = (const float*)d_in[1];
    const float* tgX  = (const float*)d_in[2];
    const float* lmD  = (const float*)d_in[4];
    const float* tgD  = (const float*)d_in[5];
    const float* Wemb = (const float*)d_in[6];
    const float* bemb = (const float*)d_in[7];
    const float* w1   = (const float*)d_in[8];
    const float* w2   = (const float*)d_in[9];

    float* out   = (float*)d_out;
    float* ypred = out;                          // [N1,2]
    float* adj   = out + 4000;                   // [NT,NT]
    float* adjT  = out + 4000 + 16000000;        // [NT,NT]

    // scratch layout in d_ws (~7.4 MB)
    char* ws = (char*)d_ws;
    unsigned short* AL    = (unsigned short*)ws;                   // 4,128,768 B
    unsigned short* Bbuf  = (unsigned short*)(ws + 4128768);       //   524,288 B
    float*          sB    = (float*)(ws + 4128768 + 524288);       //   131,072 B
    float*          partd = (float*)(ws + 4784128);                // 1,280,000 B
    int*            parti = (int*)  (ws + 6064128);                // 1,280,000 B
    int*            idx   = (int*)  (ws + 7344128);                //    40,000 B

    dim3 gk(NWIN, 32);
    k_knn<<<gk, 256, 0, stream>>>(lmX, partd, parti);
    k_mgprep<<<NT / 4, 256, 0, stream>>>(partd, parti, lmY, ypred, idx,
                                         lmX, tgX, lmD, tgD, Wemb, bemb, w1, w2,
                                         AL, Bbuf, sB);
    dim3 ga(MPAD / 256, NPAD / 64);
    k_adjm<<<ga, 256, 0, stream>>>(AL, Bbuf, sB, idx, adj, adjT);
}

// Round 9
// 210.469 us; speedup vs baseline: 1.0272x; 1.0272x over previous
//
#include <hip/hip_runtime.h>
#include <math.h>

#define N1 2000
#define N2 2000
#define NT 4000
#define D  63
#define E  64
#define H  8
#define KNN 5
#define NPAD 4032   // n padded: 63 blocks of 64
#define MPAD 4096   // m padded: 16 blocks of 256
#define NWIN 32     // knn col-windows: 32 windows of 64 cols

typedef short bf16x8 __attribute__((ext_vector_type(8)));
typedef float f32x4  __attribute__((ext_vector_type(4)));

__device__ __forceinline__ unsigned short f2bf(float x) {
    unsigned u = __float_as_uint(x);
    u = (u + 0x7fffu + ((u >> 16) & 1u)) >> 16;   // RN-even
    return (unsigned short)u;
}

// ---------------------------------------------------------------- knn helpers
__device__ __forceinline__ bool dless(float d1, int i1, float d2v, int i2) {
    return d1 < d2v || (d1 == d2v && i1 < i2);   // stable top_k tie-break
}

__device__ __forceinline__ void ins5(float bd[KNN], int bi[KNN], float d, int j) {
    if (dless(d, j, bd[KNN - 1], bi[KNN - 1])) {
        bd[KNN - 1] = d; bi[KNN - 1] = j;
        #pragma unroll
        for (int s = KNN - 1; s > 0; --s) {
            if (dless(bd[s], bi[s], bd[s - 1], bi[s - 1])) {
                float td = bd[s]; bd[s] = bd[s - 1]; bd[s - 1] = td;
                int ti = bi[s]; bi[s] = bi[s - 1]; bi[s - 1] = ti;
            }
        }
    }
}

// ---------------------------------------------------------------- k_knn
// Grid 32x32 = 1024 blocks: one 64x64 tile per block, single staging phase,
// 2 barriers, 4x4 register MAC (proven R2). Never materializes d2: per-row
// top-5 within this 64-col window via lane-local ins5 + 16-lane butterfly,
// written to part arrays (5 candidates per row per window).
__global__ __launch_bounds__(256) void k_knn(const float* __restrict__ X,
                                             float* __restrict__ part_d,
                                             int* __restrict__ part_i) {
    __shared__ float Xi[64][68];
    __shared__ float Xj[64][68];
    __shared__ float sqi[64];
    __shared__ float sqj[64];
    int cb = blockIdx.x, rb = blockIdx.y;
    int i0 = rb * 64, j0 = cb * 64;
    int tid = threadIdx.x;

    for (int t = tid; t < 64 * 64; t += 256) {
        int r = t >> 6, c = t & 63;
        int gi = min(i0 + r, N1 - 1);
        int gj = min(j0 + r, N1 - 1);
        Xi[r][c] = (c < D) ? X[gi * D + c] : 0.f;
        Xj[r][c] = (c < D) ? X[gj * D + c] : 0.f;
    }
    __syncthreads();
    if (tid < 128) {                              // sqi by lanes 0-63, sqj 64-127
        int r = tid & 63;
        const float* src = (tid < 64) ? &Xi[r][0] : &Xj[r][0];
        float s = 0.f;
        #pragma unroll
        for (int q = 0; q < 16; ++q) {
            float4 v = *(const float4*)&src[4 * q];
            s += v.x * v.x + v.y * v.y + v.z * v.z + v.w * v.w;
        }
        if (tid < 64) sqi[r] = s; else sqj[r] = s;
    }
    __syncthreads();

    int tx = tid & 15, ty = tid >> 4;
    float acc[4][4];
    #pragma unroll
    for (int a = 0; a < 4; ++a)
        #pragma unroll
        for (int b = 0; b < 4; ++b) acc[a][b] = 0.f;

    #pragma unroll 4
    for (int kk = 0; kk < 16; ++kk) {
        float4 av[4], bv[4];
        #pragma unroll
        for (int ii = 0; ii < 4; ++ii) av[ii] = *(const float4*)&Xi[ty + 16 * ii][4 * kk];
        #pragma unroll
        for (int jj = 0; jj < 4; ++jj) bv[jj] = *(const float4*)&Xj[tx + 16 * jj][4 * kk];
        #pragma unroll
        for (int ii = 0; ii < 4; ++ii)
            #pragma unroll
            for (int jj = 0; jj < 4; ++jj)
                acc[ii][jj] += av[ii].x * bv[jj].x + av[ii].y * bv[jj].y +
                               av[ii].z * bv[jj].z + av[ii].w * bv[jj].w;
    }

    // per-thread top-5 over this thread's 4 cols of each of its 4 rows
    float bd[4][KNN]; int bi[4][KNN];
    #pragma unroll
    for (int ii = 0; ii < 4; ++ii) {
        #pragma unroll
        for (int s = 0; s < KNN; ++s) { bd[ii][s] = __builtin_inff(); bi[ii][s] = 0x7fffffff; }
        int gi = i0 + ty + 16 * ii;
        float si = sqi[ty + 16 * ii];
        #pragma unroll
        for (int jj = 0; jj < 4; ++jj) {
            int gj = j0 + tx + 16 * jj;
            if (gj < N1 && gj != gi) {
                float dv = si + sqj[tx + 16 * jj] - 2.f * acc[ii][jj];
                ins5(bd[ii], bi[ii], dv, gj);
            }
        }
    }

    // merge the 16 per-lane lists of each row (16-lane butterfly, 5 extracts)
    #pragma unroll
    for (int ii = 0; ii < 4; ++ii) {
        float wd[KNN]; int wi[KNN];
        #pragma unroll
        for (int s = 0; s < KNN; ++s) {
            float d = bd[ii][0]; int ix = bi[ii][0];
            #pragma unroll
            for (int m = 1; m < 16; m <<= 1) {
                float od = __shfl_xor(d, m, 64);
                int   oi = __shfl_xor(ix, m, 64);
                if (dless(od, oi, d, ix)) { d = od; ix = oi; }
            }
            wd[s] = d; wi[s] = ix;
            if (d == bd[ii][0] && ix == bi[ii][0]) {
                #pragma unroll
                for (int q = 0; q < KNN - 1; ++q) { bd[ii][q] = bd[ii][q + 1]; bi[ii][q] = bi[ii][q + 1]; }
                bd[ii][KNN - 1] = __builtin_inff(); bi[ii][KNN - 1] = 0x7fffffff;
            }
        }
        if (tx == 0) {
            int row = i0 + ty + 16 * ii;
            if (row < N1) {
                #pragma unroll
                for (int s = 0; s < KNN; ++s) {
                    part_d[row * (NWIN * KNN) + cb * KNN + s] = wd[s];
                    part_i[row * (NWIN * KNN) + cb * KNN + s] = wi[s];
                }
            }
        }
    }
}

// ---------------------------------------------------------------- k_mgprep
// FUSED k_merge + k_prep (stream order guarantees part arrays are complete).
// Blocks < 500: first merge 4 rows (one wave per row, 32x5=160 candidates,
// 3-deep lane lists) -> ypred + idx. All 1000 blocks: prep for 4 nodes
// (1 per wave); W_emb staged in LDS. AL fold: +1/||a||. Bbuf = bf16(e).
__global__ __launch_bounds__(256) void k_mgprep(const float* __restrict__ part_d,
                                                const int* __restrict__ part_i,
                                                const float* __restrict__ lmY,
                                                float* __restrict__ ypred,
                                                int* __restrict__ idx,
                                                const float* __restrict__ lmX,
                                                const float* __restrict__ tgX,
                                                const float* __restrict__ lmD,
                                                const float* __restrict__ tgD,
                                                const float* __restrict__ W,
                                                const float* __restrict__ bias,
                                                const float* __restrict__ w1,
                                                const float* __restrict__ w2,
                                                unsigned short* __restrict__ AL,
                                                unsigned short* __restrict__ Bbuf,
                                                float* __restrict__ sB) {
    int tid = threadIdx.x, lane = tid & 63, wave = tid >> 6;

    // ---- merge phase (blocks 0..499) ----
    if (blockIdx.x < 500) {
        int row = blockIdx.x * 4 + wave;           // rows < 2000
        float ld[3]; int li[3];
        #pragma unroll
        for (int q = 0; q < 3; ++q) {
            int c = lane + 64 * q;
            if (c < NWIN * KNN) {
                ld[q] = part_d[row * (NWIN * KNN) + c];
                li[q] = part_i[row * (NWIN * KNN) + c];
            } else { ld[q] = __builtin_inff(); li[q] = 0x7fffffff; }
        }
        #pragma unroll
        for (int a = 0; a < 2; ++a)
            #pragma unroll
            for (int q = 0; q < 2; ++q)
                if (dless(ld[q + 1], li[q + 1], ld[q], li[q])) {
                    float td = ld[q]; ld[q] = ld[q + 1]; ld[q + 1] = td;
                    int ti = li[q]; li[q] = li[q + 1]; li[q + 1] = ti;
                }
        float d = ld[0]; int ix = li[0]; int p = 0;
        float rd[KNN]; int ri[KNN];
        #pragma unroll
        for (int s = 0; s < KNN; ++s) {
            float md = d; int mi = ix;
            #pragma unroll
            for (int m = 1; m < 64; m <<= 1) {
                float od = __shfl_xor(md, m, 64);
                int   oi = __shfl_xor(mi, m, 64);
                if (dless(od, oi, md, mi)) { md = od; mi = oi; }
            }
            rd[s] = md; ri[s] = mi;
            if (md == d && mi == ix) {             // this lane won: advance
                ++p;
                d  = (p < 3) ? ld[p] : __builtin_inff();
                ix = (p < 3) ? li[p] : 0x7fffffff;
            }
        }
        if (lane == 0) {
            float y0 = 0.f, y1 = 0.f;
            #pragma unroll
            for (int s = 0; s < KNN; ++s) {
                int j = ri[s];
                y0 += lmY[j * 2];
                y1 += lmY[j * 2 + 1];
                idx[row * KNN + s] = j;
            }
            ypred[row * 2]     = y0 * 0.2f;
            ypred[row * 2 + 1] = y1 * 0.2f;
        }
    }

    // ---- prep phase (all 1000 blocks, 4 nodes each) ----
    __shared__ float f[4][E];
    __shared__ float Wl[E][68];
    int n = blockIdx.x * 4 + wave;       // n < 4000
    #pragma unroll
    for (int k = 0; k < 4; ++k) {        // 1024 float4s, 4/thread, coalesced
        int g = k * 256 + tid;
        float4 v = ((const float4*)W)[g];
        int r = g >> 4, c = (g & 15) * 4;
        *(float4*)&Wl[r][c] = v;
    }
    int t = lane;
    if (t < D)  f[wave][t] = (n < N1) ? lmX[n * D + t] : tgX[(n - N1) * D + t];
    if (t == D) f[wave][t] = (n < N1) ? lmD[n] : tgD[n - N1];
    __syncthreads();
    float s0 = 0.f, s1 = 0.f, s2 = 0.f, s3 = 0.f;
    #pragma unroll
    for (int k = 0; k < 16; ++k) {
        float4 wv = *(const float4*)&Wl[t][4 * k];
        float4 fv = *(const float4*)&f[wave][4 * k];
        s0 += fv.x * wv.x; s1 += fv.y * wv.y; s2 += fv.z * wv.z; s3 += fv.w * wv.w;
    }
    const float en = bias[t] + (s0 + s1) + (s2 + s3);
    Bbuf[n * E + t] = f2bf(en);

    int kc = t >> 5, kq = (t >> 3) & 3, j = t & 7;
    int alane = kq * 16 + (n & 15);
    int nb = n >> 4;
    #pragma unroll
    for (int h = 0; h < H; ++h) {
        float a = en * w1[t * H + h];
        float b = en * w2[t * H + h];
        float na2 = a * a, nb2 = b * b;
        #pragma unroll
        for (int m = 32; m >= 1; m >>= 1) {
            na2 += __shfl_xor(na2, m, 64);
            nb2 += __shfl_xor(nb2, m, 64);
        }
        float val = a * w2[t * H + h] * rsqrtf(na2);   // folds 1/||a||
        AL[(((nb * 8 + h) << 1) + kc) * 512 + alane * 8 + j] = f2bf(val);
        if (t == h) sB[n * H + h] = rsqrtf(nb2);
    }
}

// ---------------------------------------------------------------- k_adjm
// Block: 4 waves, tile 64(n) x 256(m). B tile in LDS, A frags in registers.
// Head-halved epilogue (proven R3), __launch_bounds__(256,4).
// Polynomial sigmoid (sim in [-1,1], |err|<=5e-5).
// adj_teacher tile: base pattern (tail) + KNN scatter from precomputed idx.
// [R8 verdict: interleaving the adjT fill into the mt loop costs +5 µs
//  (store-stream contention in the latency-critical loop) -- keep the tail.]
__global__ __launch_bounds__(256, 4) void k_adjm(const unsigned short* __restrict__ AL,
                                                 const unsigned short* __restrict__ Bbuf,
                                                 const float* __restrict__ sB,
                                                 const int* __restrict__ idx,
                                                 float* __restrict__ adj,
                                                 float* __restrict__ adjT) {
    __shared__ unsigned short Bt[256][68];   // 34,816 B -> 4 blocks/CU
    int tid = threadIdx.x;
    int m0 = blockIdx.x * 256, n0 = blockIdx.y * 64;

    #pragma unroll
    for (int it = 0; it < 8; ++it) {
        int g = it * 256 + tid;
        int row = g >> 3, c = g & 7;
        *(bf16x8*)&Bt[row][c * 8] = *(const bf16x8*)&Bbuf[(m0 + row) * E + c * 8];
    }

    int wave = tid >> 6, lane = tid & 63;
    int l15 = lane & 15, kq = lane >> 4;
    int nb = blockIdx.y * 4 + wave;

    bf16x8 afr[H][2];
    #pragma unroll
    for (int h = 0; h < H; ++h)
        #pragma unroll
        for (int kc = 0; kc < 2; ++kc)
            afr[h][kc] = *(const bf16x8*)&AL[(((nb * 8 + h) << 1) + kc) * 512 + lane * 8];

    __syncthreads();

    int nebase = n0 + wave * 16 + kq * 4;

    #pragma unroll 1
    for (int mt = 0; mt < 16; ++mt) {
        int mrow = mt * 16 + l15;
        int mcol = m0 + mrow;
        bf16x8 b0 = *(const bf16x8*)&Bt[mrow][kq * 8];
        bf16x8 b1 = *(const bf16x8*)&Bt[mrow][32 + kq * 8];

        float sum[4] = {0.f, 0.f, 0.f, 0.f};
        #pragma unroll
        for (int hh = 0; hh < 2; ++hh) {
            float sbv[4];
            *(f32x4*)&sbv[0] = *(const f32x4*)&sB[mcol * H + hh * 4];
            f32x4 acc[4];
            #pragma unroll
            for (int h4 = 0; h4 < 4; ++h4) {
                int h = hh * 4 + h4;
                acc[h4] = (f32x4){0.f, 0.f, 0.f, 0.f};
                acc[h4] = __builtin_amdgcn_mfma_f32_16x16x32_bf16(afr[h][0], b0, acc[h4], 0, 0, 0);
                acc[h4] = __builtin_amdgcn_mfma_f32_16x16x32_bf16(afr[h][1], b1, acc[h4], 0, 0, 0);
            }
            #pragma unroll
            for (int reg = 0; reg < 4; ++reg) {
                #pragma unroll
                for (int h4 = 0; h4 < 4; ++h4) {
                    float x = acc[h4][reg] * sbv[h4];             // sim, in [-1,1]
                    float u = x * x;
                    float p = fmaf(u, 1.8919e-3f, -2.0833333e-2f);
                    p = fmaf(u, p, 0.25f);
                    sum[reg] = fmaf(x, p, sum[reg]);              // += sigma(x)-0.5
                }
            }
        }

        bool mok = (mcol < NT);
        #pragma unroll
        for (int reg = 0; reg < 4; ++reg) {
            int ne = nebase + reg;
            if (mok && ne < NT) adj[ne * NT + mcol] = fmaf(sum[reg], 0.125f, 0.5f);
        }
    }

    // ---- adj_teacher tile: base pattern (disjoint across blocks) ----
    #pragma unroll
    for (int it = 0; it < 16; ++it) {            // 4096 float4s / 256 thr
        int g = it * 256 + tid;
        int r = g >> 6;                          // 64 float4s per row
        int col = m0 + (g & 63) * 4;
        int row = n0 + r;
        if (row < NT && col < NT) {
            float v = ((row < N1) != (col < N1)) ? 1.f : 0.f;
            float4 o = {v, v, v, v};
            *(float4*)&adjT[row * NT + col] = o;
        }
    }
    __syncthreads();                             // order scatter after fill
    // ---- KNN scatter: rows n0..n0+63 (lm only), cols within this tile ----
    for (int p = tid; p < 64 * KNN; p += 256) {
        int r = p / KNN, s = p - r * KNN;
        int row = n0 + r;
        if (row < N1) {
            int jx = idx[row * KNN + s];
            if (jx >= m0 && jx < m0 + 256) adjT[row * NT + jx] = 1.f;
        }
    }
}

// ---------------------------------------------------------------- launch
extern "C" void kernel_launch(void* const* d_in, const int* in_sizes, int n_in,
                              void* d_out, int out_size, void* d_ws, size_t ws_size,
                              hipStream_t stream) {
    const float* lmX  = (const float*)d_in[0];
    const float* lmY  = (const float*)d_in[1];
    const float* tgX  = (const float*)d_in[2];
    const float* lmD  = (const float*)d_in[4];
    const float* tgD  = (const float*)d_in[5];
    const float* Wemb = (const float*)d_in[6];
    const float* bemb = (const float*)d_in[7];
    const float* w1   = (const float*)d_in[8];
    const float* w2   = (const float*)d_in[9];

    float* out   = (float*)d_out;
    float* ypred = out;                          // [N1,2]
    float* adj   = out + 4000;                   // [NT,NT]
    float* adjT  = out + 4000 + 16000000;        // [NT,NT]

    // scratch layout in d_ws (~7.4 MB)
    char* ws = (char*)d_ws;
    unsigned short* AL    = (unsigned short*)ws;                   // 4,128,768 B
    unsigned short* Bbuf  = (unsigned short*)(ws + 4128768);       //   524,288 B
    float*          sB    = (float*)(ws + 4128768 + 524288);       //   131,072 B
    float*          partd = (float*)(ws + 4784128);                // 1,280,000 B
    int*            parti = (int*)  (ws + 6064128);                // 1,280,000 B
    int*            idx   = (int*)  (ws + 7344128);                //    40,000 B

    dim3 gk(NWIN, 32);
    k_knn<<<gk, 256, 0, stream>>>(lmX, partd, parti);
    k_mgprep<<<NT / 4, 256, 0, stream>>>(partd, parti, lmY, ypred, idx,
                                         lmX, tgX, lmD, tgD, Wemb, bemb, w1, w2,
                                         AL, Bbuf, sB);
    dim3 ga(MPAD / 256, NPAD / 64);
    k_adjm<<<ga, 256, 0, stream>>>(AL, Bbuf, sB, idx, adj, adjT);
}